// Round 1
// baseline (241.116 us; speedup 1.0000x reference)
//
#include <hip/hip_runtime.h>

// Problem constants (from reference)
#define NP    40000            // pillars
#define NPTS  32               // points per pillar
#define CCH   64               // channels
#define BB    4
#define HH    512
#define WW    512
#define HW    (HH * WW)        // 262144 = 2^18
#define MAPN  (BB * HW)        // 1048576 spatial cells

// ---------------------------------------------------------------------------
// Kernel 1: one wave (64 lanes) per pillar.
// Each lane loads 8 float4 (coalesced 1KB per wave per instruction) covering
// the 32x64 block; lane l accumulates points {i*4 + (l>>4)} for channels
// [4*(l&15) .. 4*(l&15)+3]. Reduce across the point-group bits (4,5) via
// shfl_xor, then lanes 0..15 write the 64-channel mean row (float4 each).
// Lane 0 also writes the inverse map entry.
// ---------------------------------------------------------------------------
__global__ __launch_bounds__(256) void pillar_mean_map_kernel(
    const float* __restrict__ pf, const int* __restrict__ coords,
    float* __restrict__ feat, int* __restrict__ map) {
  int wave = threadIdx.x >> 6;
  int lane = threadIdx.x & 63;
  int p = blockIdx.x * 4 + wave;
  if (p >= NP) return;

  const float4* src = (const float4*)(pf + (size_t)p * (NPTS * CCH));
  float4 acc = make_float4(0.f, 0.f, 0.f, 0.f);
#pragma unroll
  for (int i = 0; i < 8; ++i) {
    float4 v = src[i * 64 + lane];
    acc.x += v.x; acc.y += v.y; acc.z += v.z; acc.w += v.w;
  }
  // reduce over lane bits 4 and 5 (the point-subgroup axis)
  acc.x += __shfl_xor(acc.x, 16, 64);
  acc.y += __shfl_xor(acc.y, 16, 64);
  acc.z += __shfl_xor(acc.z, 16, 64);
  acc.w += __shfl_xor(acc.w, 16, 64);
  acc.x += __shfl_xor(acc.x, 32, 64);
  acc.y += __shfl_xor(acc.y, 32, 64);
  acc.z += __shfl_xor(acc.z, 32, 64);
  acc.w += __shfl_xor(acc.w, 32, 64);

  if (lane < 16) {
    const float s = 1.0f / (float)NPTS;
    float4 o = make_float4(acc.x * s, acc.y * s, acc.z * s, acc.w * s);
    ((float4*)(feat + (size_t)p * CCH))[lane] = o;
  }
  if (lane == 0) {
    int4 cc = ((const int4*)coords)[p];  // {b, z, y, x}
    map[cc.x * HW + cc.z * WW + cc.w] = p;
  }
}

// ---------------------------------------------------------------------------
// Kernel 2: gather pass. Each thread owns 4 consecutive spatial cells
// (same b,y; x..x+3) and writes all 64 channel planes for them as float4
// (fully coalesced: a wave writes 1KB contiguous per store instruction).
// Map reads: 4MB unique (L2/L3-resident across the 64x logical reuse).
// Feat gathers: only for occupied cells (~3.8%), 10MB unique, L2-resident.
// ---------------------------------------------------------------------------
__global__ __launch_bounds__(256) void gather_out_kernel(
    const int* __restrict__ map, const float* __restrict__ feat,
    float* __restrict__ out) {
  unsigned tid = blockIdx.x * 256u + threadIdx.x;
  unsigned s = tid * 4u;                 // spatial linear index (b*HW + y*W + x)
  unsigned b = s >> 18;
  unsigned r = s & (HW - 1);             // y*W + x

  int4 pm = *(const int4*)(map + s);
  float* outb = out + ((size_t)b << 24) + r;   // b*64*HW = b<<24

  if ((pm.x & pm.y & pm.z & pm.w) < 0) {
    // all four cells empty -> pure zero fill
    float4 z = make_float4(0.f, 0.f, 0.f, 0.f);
#pragma unroll 8
    for (int c = 0; c < CCH; ++c)
      *(float4*)(outb + ((unsigned)c << 18)) = z;
  } else {
    const float* f0 = feat + (size_t)pm.x * CCH;
    const float* f1 = feat + (size_t)pm.y * CCH;
    const float* f2 = feat + (size_t)pm.z * CCH;
    const float* f3 = feat + (size_t)pm.w * CCH;
#pragma unroll 4
    for (int c = 0; c < CCH; ++c) {
      float4 v;
      v.x = (pm.x >= 0) ? f0[c] : 0.f;
      v.y = (pm.y >= 0) ? f1[c] : 0.f;
      v.z = (pm.z >= 0) ? f2[c] : 0.f;
      v.w = (pm.w >= 0) ? f3[c] : 0.f;
      *(float4*)(outb + ((unsigned)c << 18)) = v;
    }
  }
}

// ---------------------------------------------------------------------------
// Fallback (only if ws is too small): memset out + direct scatter.
// ---------------------------------------------------------------------------
__global__ __launch_bounds__(256) void pillar_scatter_direct_kernel(
    const float* __restrict__ pf, const int* __restrict__ coords,
    float* __restrict__ out) {
  int wave = threadIdx.x >> 6;
  int lane = threadIdx.x & 63;
  int p = blockIdx.x * 4 + wave;
  if (p >= NP) return;

  const float4* src = (const float4*)(pf + (size_t)p * (NPTS * CCH));
  float4 acc = make_float4(0.f, 0.f, 0.f, 0.f);
#pragma unroll
  for (int i = 0; i < 8; ++i) {
    float4 v = src[i * 64 + lane];
    acc.x += v.x; acc.y += v.y; acc.z += v.z; acc.w += v.w;
  }
  acc.x += __shfl_xor(acc.x, 16, 64);
  acc.y += __shfl_xor(acc.y, 16, 64);
  acc.z += __shfl_xor(acc.z, 16, 64);
  acc.w += __shfl_xor(acc.w, 16, 64);
  acc.x += __shfl_xor(acc.x, 32, 64);
  acc.y += __shfl_xor(acc.y, 32, 64);
  acc.z += __shfl_xor(acc.z, 32, 64);
  acc.w += __shfl_xor(acc.w, 32, 64);

  if (lane < 16) {
    int4 cc = ((const int4*)coords)[p];
    const float s = 1.0f / (float)NPTS;
    unsigned sp = (unsigned)cc.z * WW + (unsigned)cc.w;
    float* ob = out + ((size_t)cc.x << 24) + sp;
    unsigned c0 = 4u * (unsigned)lane;
    ob[(size_t)(c0 + 0) << 18] = acc.x * s;
    ob[(size_t)(c0 + 1) << 18] = acc.y * s;
    ob[(size_t)(c0 + 2) << 18] = acc.z * s;
    ob[(size_t)(c0 + 3) << 18] = acc.w * s;
  }
}

extern "C" void kernel_launch(void* const* d_in, const int* in_sizes, int n_in,
                              void* d_out, int out_size, void* d_ws, size_t ws_size,
                              hipStream_t stream) {
  const float* pf     = (const float*)d_in[0];
  const int*   coords = (const int*)d_in[1];
  float*       out    = (float*)d_out;

  const size_t map_bytes  = (size_t)MAPN * sizeof(int);        // 4 MiB
  const size_t feat_bytes = (size_t)NP * CCH * sizeof(float);  // ~10 MB

  if (ws_size >= map_bytes + feat_bytes) {
    int*   map  = (int*)d_ws;
    float* feat = (float*)((char*)d_ws + map_bytes);
    hipMemsetAsync(map, 0xFF, map_bytes, stream);  // -1 everywhere
    pillar_mean_map_kernel<<<NP / 4, 256, 0, stream>>>(pf, coords, feat, map);
    gather_out_kernel<<<MAPN / 4 / 256, 256, 0, stream>>>(map, feat, out);
  } else {
    hipMemsetAsync(out, 0, (size_t)out_size * sizeof(float), stream);
    pillar_scatter_direct_kernel<<<NP / 4, 256, 0, stream>>>(pf, coords, out);
  }
}

// Round 2
// 240.754 us; speedup vs baseline: 1.0015x; 1.0015x over previous
//
#include <hip/hip_runtime.h>

// Problem constants (from reference)
#define NP    40000            // pillars
#define NPTS  32               // points per pillar
#define CCH   64               // channels
#define BB    4
#define HH    512
#define WW    512
#define HW    (HH * WW)        // 262144 = 2^18
#define MAPN  (BB * HW)        // 1048576 spatial cells

// ---------------------------------------------------------------------------
// Kernel 0: clear the inverse map to -1. 4 MiB, int4 per thread, coalesced.
// (hipMemsetAsync's fillBufferAligned ran at 186us under graph capture — R1
// profile; this custom fill is ~2-3us.)
// ---------------------------------------------------------------------------
__global__ __launch_bounds__(256) void map_clear_kernel(int4* __restrict__ map) {
  unsigned i = blockIdx.x * 256u + threadIdx.x;
  map[i] = make_int4(-1, -1, -1, -1);
}

// ---------------------------------------------------------------------------
// Kernel 1: one wave (64 lanes) per pillar.
// Each lane loads 8 float4 (coalesced 1KB per wave per instruction) covering
// the 32x64 block; lane l accumulates points {i*4 + (l>>4)} for channels
// [4*(l&15) .. 4*(l&15)+3]. Reduce across the point-group bits (4,5) via
// shfl_xor, then lanes 0..15 write the 64-channel mean row (float4 each).
// Lane 0 also writes the inverse map entry.
// ---------------------------------------------------------------------------
__global__ __launch_bounds__(256) void pillar_mean_map_kernel(
    const float* __restrict__ pf, const int* __restrict__ coords,
    float* __restrict__ feat, int* __restrict__ map) {
  int wave = threadIdx.x >> 6;
  int lane = threadIdx.x & 63;
  int p = blockIdx.x * 4 + wave;
  if (p >= NP) return;

  const float4* src = (const float4*)(pf + (size_t)p * (NPTS * CCH));
  float4 acc = make_float4(0.f, 0.f, 0.f, 0.f);
#pragma unroll
  for (int i = 0; i < 8; ++i) {
    float4 v = src[i * 64 + lane];
    acc.x += v.x; acc.y += v.y; acc.z += v.z; acc.w += v.w;
  }
  // reduce over lane bits 4 and 5 (the point-subgroup axis)
  acc.x += __shfl_xor(acc.x, 16, 64);
  acc.y += __shfl_xor(acc.y, 16, 64);
  acc.z += __shfl_xor(acc.z, 16, 64);
  acc.w += __shfl_xor(acc.w, 16, 64);
  acc.x += __shfl_xor(acc.x, 32, 64);
  acc.y += __shfl_xor(acc.y, 32, 64);
  acc.z += __shfl_xor(acc.z, 32, 64);
  acc.w += __shfl_xor(acc.w, 32, 64);

  if (lane < 16) {
    const float s = 1.0f / (float)NPTS;
    float4 o = make_float4(acc.x * s, acc.y * s, acc.z * s, acc.w * s);
    ((float4*)(feat + (size_t)p * CCH))[lane] = o;
  }
  if (lane == 0) {
    int4 cc = ((const int4*)coords)[p];  // {b, z, y, x}
    map[cc.x * HW + cc.z * WW + cc.w] = p;
  }
}

// ---------------------------------------------------------------------------
// Kernel 2: gather pass. Each thread owns 4 consecutive spatial cells
// (same b,y; x..x+3) and writes all 64 channel planes for them as float4
// (fully coalesced: a wave writes 1KB contiguous per store instruction).
// Map reads: 4MB unique (L2/L3-resident across the 64x logical reuse).
// Feat gathers: only for occupied cells (~3.8%), 10MB unique, L2-resident.
// ---------------------------------------------------------------------------
__global__ __launch_bounds__(256) void gather_out_kernel(
    const int* __restrict__ map, const float* __restrict__ feat,
    float* __restrict__ out) {
  unsigned tid = blockIdx.x * 256u + threadIdx.x;
  unsigned s = tid * 4u;                 // spatial linear index (b*HW + y*W + x)
  unsigned b = s >> 18;
  unsigned r = s & (HW - 1);             // y*W + x

  int4 pm = *(const int4*)(map + s);
  float* outb = out + ((size_t)b << 24) + r;   // b*64*HW = b<<24

  if ((pm.x & pm.y & pm.z & pm.w) < 0) {
    // all four cells empty -> pure zero fill
    float4 z = make_float4(0.f, 0.f, 0.f, 0.f);
#pragma unroll 8
    for (int c = 0; c < CCH; ++c)
      *(float4*)(outb + ((unsigned)c << 18)) = z;
  } else {
    const float* f0 = feat + (size_t)pm.x * CCH;
    const float* f1 = feat + (size_t)pm.y * CCH;
    const float* f2 = feat + (size_t)pm.z * CCH;
    const float* f3 = feat + (size_t)pm.w * CCH;
#pragma unroll 4
    for (int c = 0; c < CCH; ++c) {
      float4 v;
      v.x = (pm.x >= 0) ? f0[c] : 0.f;
      v.y = (pm.y >= 0) ? f1[c] : 0.f;
      v.z = (pm.z >= 0) ? f2[c] : 0.f;
      v.w = (pm.w >= 0) ? f3[c] : 0.f;
      *(float4*)(outb + ((unsigned)c << 18)) = v;
    }
  }
}

// ---------------------------------------------------------------------------
// Fallback (only if ws is too small): memset out + direct scatter.
// ---------------------------------------------------------------------------
__global__ __launch_bounds__(256) void pillar_scatter_direct_kernel(
    const float* __restrict__ pf, const int* __restrict__ coords,
    float* __restrict__ out) {
  int wave = threadIdx.x >> 6;
  int lane = threadIdx.x & 63;
  int p = blockIdx.x * 4 + wave;
  if (p >= NP) return;

  const float4* src = (const float4*)(pf + (size_t)p * (NPTS * CCH));
  float4 acc = make_float4(0.f, 0.f, 0.f, 0.f);
#pragma unroll
  for (int i = 0; i < 8; ++i) {
    float4 v = src[i * 64 + lane];
    acc.x += v.x; acc.y += v.y; acc.z += v.z; acc.w += v.w;
  }
  acc.x += __shfl_xor(acc.x, 16, 64);
  acc.y += __shfl_xor(acc.y, 16, 64);
  acc.z += __shfl_xor(acc.z, 16, 64);
  acc.w += __shfl_xor(acc.w, 16, 64);
  acc.x += __shfl_xor(acc.x, 32, 64);
  acc.y += __shfl_xor(acc.y, 32, 64);
  acc.z += __shfl_xor(acc.z, 32, 64);
  acc.w += __shfl_xor(acc.w, 32, 64);

  if (lane < 16) {
    int4 cc = ((const int4*)coords)[p];
    const float s = 1.0f / (float)NPTS;
    unsigned sp = (unsigned)cc.z * WW + (unsigned)cc.w;
    float* ob = out + ((size_t)cc.x << 24) + sp;
    unsigned c0 = 4u * (unsigned)lane;
    ob[(size_t)(c0 + 0) << 18] = acc.x * s;
    ob[(size_t)(c0 + 1) << 18] = acc.y * s;
    ob[(size_t)(c0 + 2) << 18] = acc.z * s;
    ob[(size_t)(c0 + 3) << 18] = acc.w * s;
  }
}

extern "C" void kernel_launch(void* const* d_in, const int* in_sizes, int n_in,
                              void* d_out, int out_size, void* d_ws, size_t ws_size,
                              hipStream_t stream) {
  const float* pf     = (const float*)d_in[0];
  const int*   coords = (const int*)d_in[1];
  float*       out    = (float*)d_out;

  const size_t map_bytes  = (size_t)MAPN * sizeof(int);        // 4 MiB
  const size_t feat_bytes = (size_t)NP * CCH * sizeof(float);  // ~10 MB

  if (ws_size >= map_bytes + feat_bytes) {
    int*   map  = (int*)d_ws;
    float* feat = (float*)((char*)d_ws + map_bytes);
    map_clear_kernel<<<MAPN / 4 / 256, 256, 0, stream>>>((int4*)map);
    pillar_mean_map_kernel<<<NP / 4, 256, 0, stream>>>(pf, coords, feat, map);
    gather_out_kernel<<<MAPN / 4 / 256, 256, 0, stream>>>(map, feat, out);
  } else {
    // Fallback: direct scatter (note: still uses a runtime fill; only hit if
    // ws_size < 14.5 MB, which the harness doesn't do).
    hipMemsetAsync(out, 0, (size_t)out_size * sizeof(float), stream);
    pillar_scatter_direct_kernel<<<NP / 4, 256, 0, stream>>>(pf, coords, out);
  }
}